// Round 1
// baseline (1250.252 us; speedup 1.0000x reference)
//
#include <hip/hip_runtime.h>
#include <hip/hip_bf16.h>
#include <stdint.h>

// Problem constants (from reference): E=8, T=1024, D_IN=2048, D_OUT=8192
#define E_   8
#define T_   1024
#define DI_  2048
#define DO_  8192

#define BM   128
#define BN   128
#define BK   64
#define PAD  8
#define LDST (BK + PAD)   // 72 ushorts per LDS row = 144 B (16B-aligned, breaks pow2 bank stride)

typedef __attribute__((ext_vector_type(8))) short bf16x8;   // 8 bf16 = 4 VGPRs (MFMA A/B frag)
typedef __attribute__((ext_vector_type(4))) float f32x4;    // MFMA C/D frag

// Pack two fp32 into two bf16 (round-toward-zero; exact for int-valued inputs).
__device__ __forceinline__ uint32_t pack_bf16(uint32_t lo, uint32_t hi) {
    return (hi & 0xFFFF0000u) | (lo >> 16);
}

__global__ __launch_bounds__(256, 2)
void qgemm_bf16_kernel(const float* __restrict__ input,
                       const int*   __restrict__ weight,
                       const float* __restrict__ scale,
                       float*       __restrict__ out) {
    __shared__ ushort As[BM * LDST];
    __shared__ ushort Bs[BN * LDST];

    const int tid = threadIdx.x;
    const int e   = blockIdx.y;
    // m-fastest within expert: consecutive blocks share the B (weight) slab.
    const int m0 = (blockIdx.x & 7) * BM;
    const int n0 = (blockIdx.x >> 3) * BN;

    const float* Abase = input  + ((size_t)e * T_  + m0) * DI_;
    const int*   Bbase = weight + ((size_t)e * DO_ + n0) * DI_;

    // Staging decomposition: 8 contiguous elements per thread per pass.
    const int srow = tid >> 3;        // 0..31 (row within pass group)
    const int scol = (tid & 7) * 8;   // 0,8,...,56 (col within BK)

    const int lane = tid & 63;
    const int wave = tid >> 6;
    const int wm = (wave >> 1) * 64;  // wave's 64x64 subtile origin
    const int wn = (wave & 1) * 64;
    const int fr = lane & 15;         // fragment row (A) / col (B)
    const int fq = lane >> 4;         // quad: k-offset fq*8

    f32x4 acc[4][4];
    #pragma unroll
    for (int i = 0; i < 4; i++)
        #pragma unroll
        for (int j = 0; j < 4; j++)
            acc[i][j] = (f32x4){0.f, 0.f, 0.f, 0.f};

    float4 aRegs[4][2];
    int4   bRegs[4][2];

    // Prefetch tile 0 into registers.
    #pragma unroll
    for (int p = 0; p < 4; p++) {
        const float* ap = Abase + (size_t)(srow + p * 32) * DI_ + scol;
        aRegs[p][0] = *(const float4*)ap;
        aRegs[p][1] = *(const float4*)(ap + 4);
        const int* bp = Bbase + (size_t)(srow + p * 32) * DI_ + scol;
        bRegs[p][0] = *(const int4*)bp;
        bRegs[p][1] = *(const int4*)(bp + 4);
    }

    const int KT = DI_ / BK;  // 32 K-tiles
    for (int kt = 0; kt < KT; kt++) {
        // Convert staged registers -> bf16 -> LDS (ds_write_b128).
        #pragma unroll
        for (int p = 0; p < 4; p++) {
            float4 f0 = aRegs[p][0], f1 = aRegs[p][1];
            uint4 w;
            w.x = pack_bf16(__float_as_uint(f0.x), __float_as_uint(f0.y));
            w.y = pack_bf16(__float_as_uint(f0.z), __float_as_uint(f0.w));
            w.z = pack_bf16(__float_as_uint(f1.x), __float_as_uint(f1.y));
            w.w = pack_bf16(__float_as_uint(f1.z), __float_as_uint(f1.w));
            *(uint4*)&As[(srow + p * 32) * LDST + scol] = w;

            int4 i0 = bRegs[p][0], i1 = bRegs[p][1];
            uint4 v;   // int -> f32 (exact, |w|<=127) -> truncate to bf16 (exact)
            v.x = pack_bf16(__float_as_uint((float)i0.x), __float_as_uint((float)i0.y));
            v.y = pack_bf16(__float_as_uint((float)i0.z), __float_as_uint((float)i0.w));
            v.z = pack_bf16(__float_as_uint((float)i1.x), __float_as_uint((float)i1.y));
            v.w = pack_bf16(__float_as_uint((float)i1.z), __float_as_uint((float)i1.w));
            *(uint4*)&Bs[(srow + p * 32) * LDST + scol] = v;
        }
        __syncthreads();

        // Prefetch next K-tile while MFMA consumes LDS (latency hiding).
        if (kt + 1 < KT) {
            const float* An = Abase + (size_t)(kt + 1) * BK;
            const int*   Bn = Bbase + (size_t)(kt + 1) * BK;
            #pragma unroll
            for (int p = 0; p < 4; p++) {
                const float* ap = An + (size_t)(srow + p * 32) * DI_ + scol;
                aRegs[p][0] = *(const float4*)ap;
                aRegs[p][1] = *(const float4*)(ap + 4);
                const int* bp = Bn + (size_t)(srow + p * 32) * DI_ + scol;
                bRegs[p][0] = *(const int4*)bp;
                bRegs[p][1] = *(const int4*)(bp + 4);
            }
        }

        // MFMA: 2 k-steps of 32, 4x4 fragment grid per wave.
        #pragma unroll
        for (int ks = 0; ks < 2; ks++) {
            bf16x8 afrag[4], bfrag[4];
            #pragma unroll
            for (int i = 0; i < 4; i++) {
                afrag[i] = *(const bf16x8*)&As[(wm + i * 16 + fr) * LDST + ks * 32 + fq * 8];
                bfrag[i] = *(const bf16x8*)&Bs[(wn + i * 16 + fr) * LDST + ks * 32 + fq * 8];
            }
            #pragma unroll
            for (int i = 0; i < 4; i++)
                #pragma unroll
                for (int j = 0; j < 4; j++)
                    acc[i][j] = __builtin_amdgcn_mfma_f32_16x16x32_bf16(
                        afrag[i], bfrag[j], acc[i][j], 0, 0, 0);
        }
        __syncthreads();
    }

    // Epilogue: C/D layout col=lane&15, row=(lane>>4)*4+reg. Apply per-expert scale.
    const float s = scale[e];
    float* Cbase = out + ((size_t)e * T_ + m0) * DO_ + n0;
    #pragma unroll
    for (int i = 0; i < 4; i++) {
        #pragma unroll
        for (int j = 0; j < 4; j++) {
            #pragma unroll
            for (int r = 0; r < 4; r++) {
                const int row = wm + i * 16 + fq * 4 + r;
                const int col = wn + j * 16 + fr;
                Cbase[(size_t)row * DO_ + col] = acc[i][j][r] * s;
            }
        }
    }
}

extern "C" void kernel_launch(void* const* d_in, const int* in_sizes, int n_in,
                              void* d_out, int out_size, void* d_ws, size_t ws_size,
                              hipStream_t stream) {
    const float* input  = (const float*)d_in[0];
    const int*   weight = (const int*)d_in[1];
    const float* scale  = (const float*)d_in[2];
    float* out = (float*)d_out;

    dim3 grid((T_ / BM) * (DO_ / BN), E_, 1);  // 512 tiles x 8 experts = 4096 blocks
    dim3 block(256, 1, 1);
    qgemm_bf16_kernel<<<grid, block, 0, stream>>>(input, weight, scale, out);
}